// Round 3
// baseline (193.308 us; speedup 1.0000x reference)
//
#include <hip/hip_runtime.h>

#define MAXNB 64
#define CAP   128      // candidate capacity per query (expected ~35, max ~65)
#define GRID  12       // 12^3 cells, cell width 1/12 ~ 0.0833 > r = 0.08
#define NCELL (GRID * GRID * GRID)   // 1728

__device__ __forceinline__ int cell_of(float x, float y, float z) {
  int cx = min(GRID - 1, max(0, (int)(x * (float)GRID)));
  int cy = min(GRID - 1, max(0, (int)(y * (float)GRID)));
  int cz = min(GRID - 1, max(0, (int)(z * (float)GRID)));
  return (cz * GRID + cy) * GRID + cx;
}

// ---------------------------------------------------------------------------
// K1: pack xyz -> float4, compute cell, atomic slot within cell. Zero cnt.
// (pcellcnt/qcellcnt pre-zeroed via hipMemsetAsync.)
// ---------------------------------------------------------------------------
__global__ __launch_bounds__(256) void build_kernel(
    const float* __restrict__ inp, const float* __restrict__ qry,
    float4* __restrict__ ppack, float4* __restrict__ qpack,
    int* __restrict__ pcell, int* __restrict__ ppos,
    int* __restrict__ qcell, int* __restrict__ qpos,
    int* __restrict__ pcellcnt, int* __restrict__ qcellcnt,
    int* __restrict__ cnt, int n, int m) {
  int i = blockIdx.x * 256 + threadIdx.x;
  if (i < n) {
    float x = inp[3 * i], y = inp[3 * i + 1], z = inp[3 * i + 2];
    ppack[i] = make_float4(x, y, z, 0.f);
    int c = cell_of(x, y, z);
    pcell[i] = c;
    ppos[i] = atomicAdd(&pcellcnt[c], 1);
  }
  if (i < m) {
    float x = qry[3 * i], y = qry[3 * i + 1], z = qry[3 * i + 2];
    qpack[i] = make_float4(x, y, z, 0.f);
    int c = cell_of(x, y, z);
    qcell[i] = c;
    qpos[i] = atomicAdd(&qcellcnt[c], 1);
    cnt[i] = 0;
  }
}

// ---------------------------------------------------------------------------
// K2: exclusive scan of the two 1728-entry cell-count arrays (single block).
// Thread t covers elements [7t, 7t+7); Hillis-Steele over per-thread sums.
// ---------------------------------------------------------------------------
__global__ __launch_bounds__(256) void cellscan_kernel(
    const int* __restrict__ pcnt, const int* __restrict__ qcnt,
    int* __restrict__ pstart, int* __restrict__ qstart) {
  __shared__ int part[256];
  int t = threadIdx.x;
  for (int a = 0; a < 2; ++a) {
    const int* src = a ? qcnt : pcnt;
    int* dst = a ? qstart : pstart;
    int base = t * 7;
    int v[7];
    int s = 0;
#pragma unroll
    for (int i = 0; i < 7; ++i) {
      int idx = base + i;
      int c = (idx < NCELL) ? src[idx] : 0;
      v[i] = c;
      s += c;
    }
    part[t] = s;
    __syncthreads();
    for (int off = 1; off < 256; off <<= 1) {
      int vv = (t >= off) ? part[t - off] : 0;
      __syncthreads();
      part[t] += vv;
      __syncthreads();
    }
    int run = (t == 0) ? 0 : part[t - 1];
#pragma unroll
    for (int i = 0; i < 7; ++i) {
      int idx = base + i;
      if (idx <= NCELL) dst[idx] = run;  // exclusive; dst[NCELL] = total
      run += v[i];
    }
    __syncthreads();
  }
}

// ---------------------------------------------------------------------------
// K3: scatter points (pos + original idx in .w) and query ids into cell order.
// ---------------------------------------------------------------------------
__global__ __launch_bounds__(256) void scatter_kernel(
    const float4* __restrict__ ppack, const int* __restrict__ pcell,
    const int* __restrict__ ppos, const int* __restrict__ pstart,
    const int* __restrict__ qcell, const int* __restrict__ qpos,
    const int* __restrict__ qstart, float4* __restrict__ psorted,
    int* __restrict__ qorder, int n, int m) {
  int i = blockIdx.x * 256 + threadIdx.x;
  if (i < n) {
    float4 p = ppack[i];
    p.w = __int_as_float(i);
    psorted[pstart[pcell[i]] + ppos[i]] = p;
  }
  if (i < m) {
    qorder[qstart[qcell[i]] + qpos[i]] = i;
  }
}

// ---------------------------------------------------------------------------
// K4: grid scan. Thread = sorted query slot (wave-coherent cells);
// blockIdx.y = z-layer of the <=27-cell neighborhood. X-adjacent cells are
// contiguous in psorted -> one contiguous run per (z,y) row.
// ---------------------------------------------------------------------------
__global__ __launch_bounds__(256) void scan_kernel(
    const float4* __restrict__ psorted, const float4* __restrict__ qpack,
    const int* __restrict__ qorder, const int* __restrict__ pstart,
    int* __restrict__ cnt, int* __restrict__ cidx) {
#pragma clang fp contract(off)
  const float R2 = (float)(0.08 * 0.08);
  const float RM = 0.0801f;  // margin 1e-4 >> fp error, << cell slack 0.0033
  int s = blockIdx.x * 256 + threadIdx.x;
  int q = qorder[s];
  float4 Q = qpack[q];
  int x0 = max(0, (int)floorf((Q.x - RM) * (float)GRID));
  int x1 = min(GRID - 1, (int)floorf((Q.x + RM) * (float)GRID));
  int y0 = max(0, (int)floorf((Q.y - RM) * (float)GRID));
  int y1 = min(GRID - 1, (int)floorf((Q.y + RM) * (float)GRID));
  int z0 = max(0, (int)floorf((Q.z - RM) * (float)GRID));
  int z1 = min(GRID - 1, (int)floorf((Q.z + RM) * (float)GRID));
  int z = z0 + blockIdx.y;
  if (z > z1) return;
  for (int y = y0; y <= y1; ++y) {
    int rowbase = (z * GRID + y) * GRID;
    int k0 = pstart[rowbase + x0];
    int k1 = pstart[rowbase + x1 + 1];
    for (int k = k0; k < k1; ++k) {
      float4 P = psorted[k];
      float dx = Q.x - P.x;
      float dy = Q.y - P.y;
      float dz = Q.z - P.z;
      float d2 = dx * dx + dy * dy + dz * dz;  // contract OFF, matches ref
      if (d2 <= R2) {
        int slot = atomicAdd(&cnt[q], 1);
        if (slot < CAP) cidx[q * CAP + slot] = __float_as_int(P.w);
      }
    }
  }
}

// ---------------------------------------------------------------------------
// K5: one wave per query. Recompute d2 (bit-identical expression), rank by
// (d2, idx) ascending — matches top_k stable tie-break — scatter to rank slot.
// ---------------------------------------------------------------------------
__global__ __launch_bounds__(256) void rank_kernel(
    const float4* __restrict__ pts, const float4* __restrict__ qrs,
    const int* __restrict__ cnt, const int* __restrict__ cidx,
    int* __restrict__ nbr) {
#pragma clang fp contract(off)
  __shared__ float sd2[4][CAP];
  __shared__ int sidx[4][CAP];
  __shared__ int souts[4][MAXNB];
  int w = threadIdx.x >> 6;
  int lane = threadIdx.x & 63;
  int q = blockIdx.x * 4 + w;
  float4 Q = qrs[q];
  int raw = cnt[q];
  int nc = raw < CAP ? raw : CAP;

  for (int c = lane; c < nc; c += 64) {
    int id = cidx[q * CAP + c];
    float4 P = pts[id];
    float dx = Q.x - P.x;
    float dy = Q.y - P.y;
    float dz = Q.z - P.z;
    sd2[w][c] = dx * dx + dy * dy + dz * dz;
    sidx[w][c] = id;
  }
  souts[w][lane] = -1;
  __syncthreads();

  for (int c = lane; c < nc; c += 64) {
    float myd = sd2[w][c];
    int myi = sidx[w][c];
    int rank = 0;
    for (int j = 0; j < nc; ++j) {
      float dj = sd2[w][j];
      int ij = sidx[w][j];
      rank += (dj < myd) || (dj == myd && ij < myi);
    }
    if (rank < MAXNB) souts[w][rank] = myi;
  }
  __syncthreads();

  nbr[(size_t)q * MAXNB + lane] = souts[w][lane];
}

// ---------------------------------------------------------------------------
// K6: row_splits = [0, cumsum(min(cnt,64))]. Single block, int4 loads.
// ---------------------------------------------------------------------------
__global__ __launch_bounds__(256) void splits_kernel(
    const int* __restrict__ cnt, int* __restrict__ rs, int m) {
  __shared__ int part[256];
  int t = threadIdx.x;
  int per = m / 256;  // 64
  int base = t * per;
  const int4* c4 = (const int4*)(cnt + base);
  int s = 0;
#pragma unroll
  for (int i = 0; i < 16; ++i) {
    int4 v = c4[i];
    s += min(v.x, MAXNB) + min(v.y, MAXNB) + min(v.z, MAXNB) + min(v.w, MAXNB);
  }
  part[t] = s;
  __syncthreads();
  for (int off = 1; off < 256; off <<= 1) {
    int v = (t >= off) ? part[t - off] : 0;
    __syncthreads();
    part[t] += v;
    __syncthreads();
  }
  int run = (t == 0) ? 0 : part[t - 1];
  if (t == 0) rs[0] = 0;
#pragma unroll
  for (int i = 0; i < 16; ++i) {
    int4 v = c4[i];
    run += min(v.x, MAXNB); rs[base + 4 * i + 1] = run;
    run += min(v.y, MAXNB); rs[base + 4 * i + 2] = run;
    run += min(v.z, MAXNB); rs[base + 4 * i + 3] = run;
    run += min(v.w, MAXNB); rs[base + 4 * i + 4] = run;
  }
}

// ---------------------------------------------------------------------------
extern "C" void kernel_launch(void* const* d_in, const int* in_sizes, int n_in,
                              void* d_out, int out_size, void* d_ws, size_t ws_size,
                              hipStream_t stream) {
  const float* inp = (const float*)d_in[0];  // inp_positions [N,3]
  const float* qry = (const float*)d_in[1];  // out_positions [M,3]
  int n = in_sizes[0] / 3;
  int m = in_sizes[1] / 3;

  char* ws = (char*)d_ws;
  size_t off = 0;
  float4* ppack   = (float4*)(ws + off); off += (size_t)n * 16;
  float4* qpack   = (float4*)(ws + off); off += (size_t)m * 16;
  float4* psorted = (float4*)(ws + off); off += (size_t)n * 16;
  int* qorder   = (int*)(ws + off); off += (size_t)m * 4;
  int* pcell    = (int*)(ws + off); off += (size_t)n * 4;
  int* ppos     = (int*)(ws + off); off += (size_t)n * 4;
  int* qcell    = (int*)(ws + off); off += (size_t)m * 4;
  int* qpos     = (int*)(ws + off); off += (size_t)m * 4;
  int* cnt      = (int*)(ws + off); off += (size_t)m * 4;
  int* pcellcnt = (int*)(ws + off); off += (size_t)NCELL * 4;
  int* qcellcnt = (int*)(ws + off); off += (size_t)NCELL * 4;
  int* pstart   = (int*)(ws + off); off += (size_t)(NCELL + 1) * 4;
  int* qstart   = (int*)(ws + off); off += (size_t)(NCELL + 1) * 4;
  int* cidx     = (int*)(ws + off); off += (size_t)m * CAP * 4;

  int* nbr = (int*)d_out;             // [m, 64]
  int* rs = nbr + (size_t)m * MAXNB;  // [m+1]

  // zero the two adjacent cell-count arrays in one memset
  hipMemsetAsync(pcellcnt, 0, (size_t)NCELL * 2 * 4, stream);

  int mx = n > m ? n : m;
  hipLaunchKernelGGL(build_kernel, dim3((mx + 255) / 256), dim3(256), 0, stream,
                     inp, qry, ppack, qpack, pcell, ppos, qcell, qpos,
                     pcellcnt, qcellcnt, cnt, n, m);
  hipLaunchKernelGGL(cellscan_kernel, dim3(1), dim3(256), 0, stream,
                     pcellcnt, qcellcnt, pstart, qstart);
  hipLaunchKernelGGL(scatter_kernel, dim3((mx + 255) / 256), dim3(256), 0, stream,
                     ppack, pcell, ppos, pstart, qcell, qpos, qstart,
                     psorted, qorder, n, m);
  hipLaunchKernelGGL(scan_kernel, dim3(m / 256, 3), dim3(256), 0, stream,
                     psorted, qpack, qorder, pstart, cnt, cidx);
  hipLaunchKernelGGL(rank_kernel, dim3(m / 4), dim3(256), 0, stream,
                     ppack, qpack, cnt, cidx, nbr);
  hipLaunchKernelGGL(splits_kernel, dim3(1), dim3(256), 0, stream, cnt, rs, m);
}

// Round 4
// 97.093 us; speedup vs baseline: 1.9910x; 1.9910x over previous
//
#include <hip/hip_runtime.h>

#define MAXNB 64
#define CAP   128      // candidate capacity per query (expected ~35, max ~65)
#define GRID  12       // 12^3 cells, cell width 1/12 ~ 0.0833 > r = 0.08
#define NCELL (GRID * GRID * GRID)   // 1728

__device__ __forceinline__ int cell_of(float x, float y, float z) {
  int cx = min(GRID - 1, max(0, (int)(x * (float)GRID)));
  int cy = min(GRID - 1, max(0, (int)(y * (float)GRID)));
  int cz = min(GRID - 1, max(0, (int)(z * (float)GRID)));
  return (cz * GRID + cy) * GRID + cx;
}

// ---------------------------------------------------------------------------
// K1: pack xyz -> float4 (points + queries), point cell + slot via atomic.
// ---------------------------------------------------------------------------
__global__ __launch_bounds__(256) void build_kernel(
    const float* __restrict__ inp, const float* __restrict__ qry,
    float4* __restrict__ ppack, float4* __restrict__ qpack,
    int* __restrict__ pcell, int* __restrict__ ppos,
    int* __restrict__ pcellcnt, int n, int m) {
  int i = blockIdx.x * 256 + threadIdx.x;
  if (i < n) {
    float x = inp[3 * i], y = inp[3 * i + 1], z = inp[3 * i + 2];
    ppack[i] = make_float4(x, y, z, 0.f);
    int c = cell_of(x, y, z);
    pcell[i] = c;
    ppos[i] = atomicAdd(&pcellcnt[c], 1);
  }
  if (i < m) {
    qpack[i] = make_float4(qry[3 * i], qry[3 * i + 1], qry[3 * i + 2], 0.f);
  }
}

// ---------------------------------------------------------------------------
// K2: exclusive scan of the 1728-entry point cell counts (single block).
// ---------------------------------------------------------------------------
__global__ __launch_bounds__(256) void cellscan_kernel(
    const int* __restrict__ pcnt, int* __restrict__ pstart) {
  __shared__ int part[256];
  int t = threadIdx.x;
  int base = t * 7;
  int v[7];
  int s = 0;
#pragma unroll
  for (int i = 0; i < 7; ++i) {
    int idx = base + i;
    int c = (idx < NCELL) ? pcnt[idx] : 0;
    v[i] = c;
    s += c;
  }
  part[t] = s;
  __syncthreads();
  for (int off = 1; off < 256; off <<= 1) {
    int vv = (t >= off) ? part[t - off] : 0;
    __syncthreads();
    part[t] += vv;
    __syncthreads();
  }
  int run = (t == 0) ? 0 : part[t - 1];
#pragma unroll
  for (int i = 0; i < 7; ++i) {
    int idx = base + i;
    if (idx <= NCELL) pstart[idx] = run;  // exclusive; pstart[NCELL] = total
    run += v[i];
  }
}

// ---------------------------------------------------------------------------
// K3: scatter points into cell order; original index kept in .w.
// ---------------------------------------------------------------------------
__global__ __launch_bounds__(256) void scatter_kernel(
    const float4* __restrict__ ppack, const int* __restrict__ pcell,
    const int* __restrict__ ppos, const int* __restrict__ pstart,
    float4* __restrict__ psorted, int n) {
  int i = blockIdx.x * 256 + threadIdx.x;
  if (i < n) {
    float4 p = ppack[i];
    p.w = __int_as_float(i);
    psorted[pstart[pcell[i]] + ppos[i]] = p;
  }
}

// ---------------------------------------------------------------------------
// K4: fused scan+rank. One WAVE per query. Lanes sweep each contiguous
// x-row of the <=27-cell neighborhood; hits compacted into LDS via
// ballot+mbcnt (no atomics, nc stays wave-uniform). Then rank candidates
// by (d2, idx) ascending — matches top_k(-d2) stable tie-break — and write
// the 64 outputs coalesced. d2 expression is contract-OFF, identical to ref.
// ---------------------------------------------------------------------------
__global__ __launch_bounds__(256) void scanrank_kernel(
    const float4* __restrict__ psorted, const float4* __restrict__ qpack,
    const int* __restrict__ pstart, int* __restrict__ cnt,
    int* __restrict__ nbr) {
#pragma clang fp contract(off)
  const float R2 = (float)(0.08 * 0.08);
  const float RM = 0.0801f;  // margin 1e-4 >> fp error, << cell slack 0.0033
  __shared__ float sd2[4][CAP];
  __shared__ int sidx[4][CAP];
  __shared__ int souts[4][MAXNB];
  int w = threadIdx.x >> 6;
  int lane = threadIdx.x & 63;
  int q = blockIdx.x * 4 + w;
  float4 Q = qpack[q];  // uniform per wave -> broadcast load

  int x0 = max(0, (int)floorf((Q.x - RM) * (float)GRID));
  int x1 = min(GRID - 1, (int)floorf((Q.x + RM) * (float)GRID));
  int y0 = max(0, (int)floorf((Q.y - RM) * (float)GRID));
  int y1 = min(GRID - 1, (int)floorf((Q.y + RM) * (float)GRID));
  int z0 = max(0, (int)floorf((Q.z - RM) * (float)GRID));
  int z1 = min(GRID - 1, (int)floorf((Q.z + RM) * (float)GRID));

  int nc = 0;  // wave-uniform running hit count
  for (int z = z0; z <= z1; ++z) {
    for (int y = y0; y <= y1; ++y) {
      int rowbase = (z * GRID + y) * GRID;
      int k0 = pstart[rowbase + x0];
      int k1 = pstart[rowbase + x1 + 1];
      for (int kb = k0; kb < k1; kb += 64) {  // uniform trip count
        int k = kb + lane;
        bool hit = false;
        float d2 = 0.f;
        int id = 0;
        if (k < k1) {
          float4 P = psorted[k];
          float dx = Q.x - P.x;
          float dy = Q.y - P.y;
          float dz = Q.z - P.z;
          d2 = dx * dx + dy * dy + dz * dz;  // contract OFF, matches ref
          id = __float_as_int(P.w);
          hit = d2 <= R2;
        }
        unsigned long long b = __ballot(hit);
        int pre = __builtin_amdgcn_mbcnt_hi(
            (unsigned)(b >> 32), __builtin_amdgcn_mbcnt_lo((unsigned)b, 0));
        int slot = nc + pre;
        if (hit && slot < CAP) {
          sd2[w][slot] = d2;
          sidx[w][slot] = id;
        }
        nc += __popcll(b);
      }
    }
  }

  if (lane == 0) cnt[q] = nc;  // raw count; splits clamps to 64
  souts[w][lane] = -1;
  __syncthreads();

  int ncc = nc < CAP ? nc : CAP;
  for (int c = lane; c < ncc; c += 64) {
    float myd = sd2[w][c];
    int myi = sidx[w][c];
    int rank = 0;
    for (int j = 0; j < ncc; ++j) {  // broadcast LDS reads, no conflicts
      float dj = sd2[w][j];
      int ij = sidx[w][j];
      rank += (dj < myd) || (dj == myd && ij < myi);
    }
    if (rank < MAXNB) souts[w][rank] = myi;
  }
  __syncthreads();

  nbr[(size_t)q * MAXNB + lane] = souts[w][lane];
}

// ---------------------------------------------------------------------------
// K5: row_splits = [0, cumsum(min(cnt,64))]. Single block, int4 loads.
// ---------------------------------------------------------------------------
__global__ __launch_bounds__(256) void splits_kernel(
    const int* __restrict__ cnt, int* __restrict__ rs, int m) {
  __shared__ int part[256];
  int t = threadIdx.x;
  int per = m / 256;  // 64
  int base = t * per;
  const int4* c4 = (const int4*)(cnt + base);
  int s = 0;
#pragma unroll
  for (int i = 0; i < 16; ++i) {
    int4 v = c4[i];
    s += min(v.x, MAXNB) + min(v.y, MAXNB) + min(v.z, MAXNB) + min(v.w, MAXNB);
  }
  part[t] = s;
  __syncthreads();
  for (int off = 1; off < 256; off <<= 1) {
    int v = (t >= off) ? part[t - off] : 0;
    __syncthreads();
    part[t] += v;
    __syncthreads();
  }
  int run = (t == 0) ? 0 : part[t - 1];
  if (t == 0) rs[0] = 0;
#pragma unroll
  for (int i = 0; i < 16; ++i) {
    int4 v = c4[i];
    run += min(v.x, MAXNB); rs[base + 4 * i + 1] = run;
    run += min(v.y, MAXNB); rs[base + 4 * i + 2] = run;
    run += min(v.z, MAXNB); rs[base + 4 * i + 3] = run;
    run += min(v.w, MAXNB); rs[base + 4 * i + 4] = run;
  }
}

// ---------------------------------------------------------------------------
extern "C" void kernel_launch(void* const* d_in, const int* in_sizes, int n_in,
                              void* d_out, int out_size, void* d_ws, size_t ws_size,
                              hipStream_t stream) {
  const float* inp = (const float*)d_in[0];  // inp_positions [N,3]
  const float* qry = (const float*)d_in[1];  // out_positions [M,3]
  int n = in_sizes[0] / 3;
  int m = in_sizes[1] / 3;

  char* ws = (char*)d_ws;
  size_t off = 0;
  float4* ppack   = (float4*)(ws + off); off += (size_t)n * 16;
  float4* qpack   = (float4*)(ws + off); off += (size_t)m * 16;
  float4* psorted = (float4*)(ws + off); off += (size_t)n * 16;
  int* pcell    = (int*)(ws + off); off += (size_t)n * 4;
  int* ppos     = (int*)(ws + off); off += (size_t)n * 4;
  int* cnt      = (int*)(ws + off); off += (size_t)m * 4;
  int* pcellcnt = (int*)(ws + off); off += (size_t)NCELL * 4;
  int* pstart   = (int*)(ws + off); off += (size_t)(NCELL + 1) * 4;

  int* nbr = (int*)d_out;             // [m, 64]
  int* rs = nbr + (size_t)m * MAXNB;  // [m+1]

  hipMemsetAsync(pcellcnt, 0, (size_t)NCELL * 4, stream);

  int mx = n > m ? n : m;
  hipLaunchKernelGGL(build_kernel, dim3((mx + 255) / 256), dim3(256), 0, stream,
                     inp, qry, ppack, qpack, pcell, ppos, pcellcnt, n, m);
  hipLaunchKernelGGL(cellscan_kernel, dim3(1), dim3(256), 0, stream,
                     pcellcnt, pstart);
  hipLaunchKernelGGL(scatter_kernel, dim3((n + 255) / 256), dim3(256), 0, stream,
                     ppack, pcell, ppos, pstart, psorted, n);
  hipLaunchKernelGGL(scanrank_kernel, dim3(m / 4), dim3(256), 0, stream,
                     psorted, qpack, pstart, cnt, nbr);
  hipLaunchKernelGGL(splits_kernel, dim3(1), dim3(256), 0, stream, cnt, rs, m);
}

// Round 6
// 93.005 us; speedup vs baseline: 2.0785x; 1.0440x over previous
//
#include <hip/hip_runtime.h>

#define MAXNB 64
#define CAP   128      // candidate capacity per query (expected ~35, max ~65)
#define GRID  12       // 12^3 cells, cell width 1/12 ~ 0.0833 > r = 0.08
#define NCELL (GRID * GRID * GRID)   // 1728

__device__ __forceinline__ int cell_of(float x, float y, float z) {
  int cx = min(GRID - 1, max(0, (int)(x * (float)GRID)));
  int cy = min(GRID - 1, max(0, (int)(y * (float)GRID)));
  int cz = min(GRID - 1, max(0, (int)(z * (float)GRID)));
  return (cz * GRID + cy) * GRID + cx;
}

// ---------------------------------------------------------------------------
// K1: point cell + slot via atomic; pack queries -> float4.
// ---------------------------------------------------------------------------
__global__ __launch_bounds__(256) void build_kernel(
    const float* __restrict__ inp, const float* __restrict__ qry,
    float4* __restrict__ qpack, int* __restrict__ pcell, int* __restrict__ ppos,
    int* __restrict__ pcellcnt, int n, int m) {
  int i = blockIdx.x * 256 + threadIdx.x;
  if (i < n) {
    float x = inp[3 * i], y = inp[3 * i + 1], z = inp[3 * i + 2];
    int c = cell_of(x, y, z);
    pcell[i] = c;
    ppos[i] = atomicAdd(&pcellcnt[c], 1);
  }
  if (i < m) {
    qpack[i] = make_float4(qry[3 * i], qry[3 * i + 1], qry[3 * i + 2], 0.f);
  }
}

// ---------------------------------------------------------------------------
// K2: exclusive scan of the 1728-entry point cell counts (single block).
// ---------------------------------------------------------------------------
__global__ __launch_bounds__(256) void cellscan_kernel(
    const int* __restrict__ pcnt, int* __restrict__ pstart) {
  __shared__ int part[256];
  int t = threadIdx.x;
  int base = t * 7;
  int v[7];
  int s = 0;
#pragma unroll
  for (int i = 0; i < 7; ++i) {
    int idx = base + i;
    int c = (idx < NCELL) ? pcnt[idx] : 0;
    v[i] = c;
    s += c;
  }
  part[t] = s;
  __syncthreads();
  for (int off = 1; off < 256; off <<= 1) {
    int vv = (t >= off) ? part[t - off] : 0;
    __syncthreads();
    part[t] += vv;
    __syncthreads();
  }
  int run = (t == 0) ? 0 : part[t - 1];
#pragma unroll
  for (int i = 0; i < 7; ++i) {
    int idx = base + i;
    if (idx <= NCELL) pstart[idx] = run;  // exclusive; pstart[NCELL] = total
    run += v[i];
  }
}

// ---------------------------------------------------------------------------
// K3: scatter points into cell order directly from inp; orig index in .w.
// ---------------------------------------------------------------------------
__global__ __launch_bounds__(256) void scatter_kernel(
    const float* __restrict__ inp, const int* __restrict__ pcell,
    const int* __restrict__ ppos, const int* __restrict__ pstart,
    float4* __restrict__ psorted, int n) {
  int i = blockIdx.x * 256 + threadIdx.x;
  if (i < n) {
    float4 p = make_float4(inp[3 * i], inp[3 * i + 1], inp[3 * i + 2],
                           __int_as_float(i));
    psorted[pstart[pcell[i]] + ppos[i]] = p;
  }
}

// ---------------------------------------------------------------------------
// K4: fused scan+rank, one WAVE per query, no block barriers (each wave owns
// its LDS slice). Row ranges of the <=27-cell neighborhood are resolved into
// a per-wave LDS table, then swept as ONE flat index range. The sweep loop
// has a UNIFORM trip count (tb uniform, masked tail) so every lane sees
// every ballot and nc stays wave-uniform — this was the R4 bug (per-lane
// trip count left high lanes' nc under-counted, corrupting the rank phase).
// Hits compacted via ballot+mbcnt into packed u64 keys
// (f32bits(d2)<<32 | idx); rank = count of smaller keys == top_k(-d2) order.
// d2 expression contract-OFF, bit-identical to the reference.
// ---------------------------------------------------------------------------
__global__ __launch_bounds__(256) void scanrank_kernel(
    const float4* __restrict__ psorted, const float4* __restrict__ qpack,
    const int* __restrict__ pstart, int* __restrict__ cnt,
    int* __restrict__ nbr) {
#pragma clang fp contract(off)
  const float R2 = (float)(0.08 * 0.08);
  const float RM = 0.0801f;  // margin 1e-4 >> fp error, << cell slack 0.0033
  __shared__ unsigned long long skey[4][CAP];
  __shared__ int srk0[4][10];   // row start index in psorted
  __shared__ int sracc[4][10];  // prefix of row lengths
  __shared__ int souts[4][MAXNB];
  int w = threadIdx.x >> 6;
  int lane = threadIdx.x & 63;
  int q = blockIdx.x * 4 + w;
  float4 Q = qpack[q];  // wave-uniform

  int x0 = max(0, (int)floorf((Q.x - RM) * (float)GRID));
  int x1 = min(GRID - 1, (int)floorf((Q.x + RM) * (float)GRID));
  int y0 = max(0, (int)floorf((Q.y - RM) * (float)GRID));
  int y1 = min(GRID - 1, (int)floorf((Q.y + RM) * (float)GRID));
  int z0 = max(0, (int)floorf((Q.z - RM) * (float)GRID));
  int z1 = min(GRID - 1, (int)floorf((Q.z + RM) * (float)GRID));

  // Build the row table (wave-uniform; lane 0 writes LDS).
  int nr = 0, tot = 0;
  for (int z = z0; z <= z1; ++z) {
    for (int y = y0; y <= y1; ++y) {
      int rb = (z * GRID + y) * GRID;
      int k0 = pstart[rb + x0];       // same addr all lanes -> broadcast
      int k1 = pstart[rb + x1 + 1];
      if (lane == 0) { srk0[w][nr] = k0; sracc[w][nr] = tot; }
      tot += k1 - k0;
      ++nr;
    }
  }

  // Flat sweep over all candidate points. UNIFORM trip count: all lanes
  // execute every ballot round -> nc stays wave-uniform.
  int nc = 0;
  for (int tb = 0; tb < tot; tb += 64) {
    int t = tb + lane;
    bool hit = false;
    float d2 = 0.f;
    int id = 0;
    if (t < tot) {
      int r = 0;
#pragma unroll
      for (int s = 1; s < 9; ++s)
        if (s < nr && t >= sracc[w][s]) r = s;
      int k = srk0[w][r] + (t - sracc[w][r]);
      float4 P = psorted[k];
      float dx = Q.x - P.x;
      float dy = Q.y - P.y;
      float dz = Q.z - P.z;
      d2 = dx * dx + dy * dy + dz * dz;  // contract OFF, matches ref
      id = __float_as_int(P.w);
      hit = d2 <= R2;
    }
    unsigned long long b = __ballot(hit);
    int pre = __builtin_amdgcn_mbcnt_hi(
        (unsigned)(b >> 32), __builtin_amdgcn_mbcnt_lo((unsigned)b, 0));
    int slot = nc + pre;
    if (hit && slot < CAP) {
      skey[w][slot] =
          ((unsigned long long)(unsigned)__float_as_int(d2) << 32) |
          (unsigned)id;
    }
    nc += __popcll(b);
  }

  if (lane == 0) cnt[q] = nc;  // raw count; splits clamps to 64
  souts[w][lane] = -1;

  int ncc = nc < CAP ? nc : CAP;
  for (int c = lane; c < ncc; c += 64) {
    unsigned long long mykey = skey[w][c];
    int rank = 0;
    for (int j = 0; j < ncc; ++j)         // ds_read_b64 broadcast
      rank += (skey[w][j] < mykey);
    if (rank < MAXNB) souts[w][rank] = (int)(unsigned)mykey;
  }

  nbr[(size_t)q * MAXNB + lane] = souts[w][lane];
}

// ---------------------------------------------------------------------------
// K5: row_splits = [0, cumsum(min(cnt,64))]. Single block, int4 loads.
// ---------------------------------------------------------------------------
__global__ __launch_bounds__(256) void splits_kernel(
    const int* __restrict__ cnt, int* __restrict__ rs, int m) {
  __shared__ int part[256];
  int t = threadIdx.x;
  int per = m / 256;  // 64
  int base = t * per;
  const int4* c4 = (const int4*)(cnt + base);
  int s = 0;
#pragma unroll
  for (int i = 0; i < 16; ++i) {
    int4 v = c4[i];
    s += min(v.x, MAXNB) + min(v.y, MAXNB) + min(v.z, MAXNB) + min(v.w, MAXNB);
  }
  part[t] = s;
  __syncthreads();
  for (int off = 1; off < 256; off <<= 1) {
    int v = (t >= off) ? part[t - off] : 0;
    __syncthreads();
    part[t] += v;
    __syncthreads();
  }
  int run = (t == 0) ? 0 : part[t - 1];
  if (t == 0) rs[0] = 0;
#pragma unroll
  for (int i = 0; i < 16; ++i) {
    int4 v = c4[i];
    run += min(v.x, MAXNB); rs[base + 4 * i + 1] = run;
    run += min(v.y, MAXNB); rs[base + 4 * i + 2] = run;
    run += min(v.z, MAXNB); rs[base + 4 * i + 3] = run;
    run += min(v.w, MAXNB); rs[base + 4 * i + 4] = run;
  }
}

// ---------------------------------------------------------------------------
extern "C" void kernel_launch(void* const* d_in, const int* in_sizes, int n_in,
                              void* d_out, int out_size, void* d_ws, size_t ws_size,
                              hipStream_t stream) {
  const float* inp = (const float*)d_in[0];  // inp_positions [N,3]
  const float* qry = (const float*)d_in[1];  // out_positions [M,3]
  int n = in_sizes[0] / 3;
  int m = in_sizes[1] / 3;

  char* ws = (char*)d_ws;
  size_t off = 0;
  float4* qpack   = (float4*)(ws + off); off += (size_t)m * 16;
  float4* psorted = (float4*)(ws + off); off += (size_t)n * 16;
  int* pcell    = (int*)(ws + off); off += (size_t)n * 4;
  int* ppos     = (int*)(ws + off); off += (size_t)n * 4;
  int* cnt      = (int*)(ws + off); off += (size_t)m * 4;
  int* pcellcnt = (int*)(ws + off); off += (size_t)NCELL * 4;
  int* pstart   = (int*)(ws + off); off += (size_t)(NCELL + 1) * 4;

  int* nbr = (int*)d_out;             // [m, 64]
  int* rs = nbr + (size_t)m * MAXNB;  // [m+1]

  hipMemsetAsync(pcellcnt, 0, (size_t)NCELL * 4, stream);

  int mx = n > m ? n : m;
  hipLaunchKernelGGL(build_kernel, dim3((mx + 255) / 256), dim3(256), 0, stream,
                     inp, qry, qpack, pcell, ppos, pcellcnt, n, m);
  hipLaunchKernelGGL(cellscan_kernel, dim3(1), dim3(256), 0, stream,
                     pcellcnt, pstart);
  hipLaunchKernelGGL(scatter_kernel, dim3((n + 255) / 256), dim3(256), 0, stream,
                     inp, pcell, ppos, pstart, psorted, n);
  hipLaunchKernelGGL(scanrank_kernel, dim3(m / 4), dim3(256), 0, stream,
                     psorted, qpack, pstart, cnt, nbr);
  hipLaunchKernelGGL(splits_kernel, dim3(1), dim3(256), 0, stream, cnt, rs, m);
}